// Round 5
// baseline (152.065 us; speedup 1.0000x reference)
//
#include <hip/hip_runtime.h>

// InvWarpFlow: out[b,y,x,c] = bilinear(img[b], (y + flow[b,y,x,0], x + flow[b,y,x,1]))
// (reference is dense_image_warp(img, -flow), so query = grid + flow)
// img:  [16,256,512,32] f32 ; flow: [16,256,512,2] f32 ; out: [16,256,512,32] f32
//
// R4 lesson: gather is capped by per-CU miss-queue x L3 first-touch latency
// (~64 lines x ~600cy = 3.7 TB/s aggregate — exactly observed). Fix: stream-
// prefetch each tile's img rows (+/-6-row margin) via global_load_lds into a
// dump LDS buffer, turning data-dependent first-touch into a deep pipelined
// stream; the gathers then MSHR-merge / hit L2.

typedef float floatx4 __attribute__((ext_vector_type(4)));

__global__ __launch_bounds__(256) void InvWarpFlow_kernel(
    const float* __restrict__ img,
    const float* __restrict__ flow,
    float* __restrict__ out)
{
    constexpr int H = 256, W = 512, C = 32;
    constexpr int TW = 8, TH = 16, MG = 6;          // tile 8x16 px, 6-row margin
    constexpr int TILES_X = W / TW;                 // 64
    constexpr int TILES_Y = H / TH;                 // 16
    constexpr int NBLK = 16 * TILES_X * TILES_Y;    // 16384
    constexpr int PER_XCD = NBLK / 8;               // 2048

    __shared__ float dump[256];                     // 1 KB prefetch sink (never read)

    // XCD-chunked swizzle; within a chunk tx varies fastest (band sweep),
    // so x-adjacent tiles are concurrent on the same XCD (covers x-margin).
    int bid = blockIdx.x;
    int logical = (bid & 7) * PER_XCD + (bid >> 3);

    int tx = logical & (TILES_X - 1);
    int r  = logical >> 6;
    int ty = r & (TILES_Y - 1);
    int b  = r >> 4;

    int t  = threadIdx.x;
    int cg = t & 7;                  // channel group (float4)
    int s  = t >> 3;                 // pixel slot 0..31
    int lx = s & 7;
    int wv = s >> 3;                 // wave id 0..3

    int x  = tx * TW + lx;
    int y0 = ty * TH + wv * 4;       // this thread's 4 rows: y0..y0+3
    int pix0 = ((b << 8) + y0) * W + x;

    // 1) flow loads first (needed to form gather addresses).
    float2 f[4];
    #pragma unroll
    for (int k = 0; k < 4; ++k)
        f[k] = *reinterpret_cast<const float2*>(flow + (size_t)(pix0 + k * W) * 2);

    const float* ibase = img + (size_t)b * H * W * C;

    // 2) streaming prefetch of tile rows [y0t-6, y0t+25] x tile columns.
    //    32 rows x 8 px x 128 B = 32 KB per block; 8 x 16B loads per thread,
    //    all independent, sunk into LDS (no VGPRs, no waits).
    {
        int x0t = tx * TW, y0t = ty * TH;
        #pragma unroll
        for (int i = 0; i < 8; ++i) {
            int l  = t + i * 256;            // 0..2047
            int rr = l >> 6;                 // row 0..31
            int cc = l & 63;                 // 16B slot within 1KB row-chunk
            int yr = min(max(y0t - MG + rr, 0), H - 1);
            const float* p = ibase + ((size_t)yr * W + x0t) * C + cc * 4;
            __builtin_amdgcn_global_load_lds(
                (const __attribute__((address_space(1))) float*)p,
                (__attribute__((address_space(3))) float*)dump, 16, 0, 0);
        }
    }

    // 3) gather + bilinear.
    const float* ib = ibase + cg * 4;
    floatx4 tl[4], tr[4], bl[4], br[4];
    float ax[4], ay[4];
    #pragma unroll
    for (int k = 0; k < 4; ++k) {
        float qy = (float)(y0 + k) + f[k].x;
        float qx = (float)x + f[k].y;
        float fy = fminf(fmaxf(floorf(qy), 0.0f), (float)(H - 2));
        float fx = fminf(fmaxf(floorf(qx), 0.0f), (float)(W - 2));
        ay[k] = fminf(fmaxf(qy - fy, 0.0f), 1.0f);
        ax[k] = fminf(fmaxf(qx - fx, 0.0f), 1.0f);
        int iy = (int)fy;
        int ix = (int)fx;
        const float* base = ib + ((size_t)iy * W + ix) * C;
        tl[k] = *reinterpret_cast<const floatx4*>(base);
        tr[k] = *reinterpret_cast<const floatx4*>(base + C);
        bl[k] = *reinterpret_cast<const floatx4*>(base + (size_t)W * C);
        br[k] = *reinterpret_cast<const floatx4*>(base + (size_t)W * C + C);
    }

    #pragma unroll
    for (int k = 0; k < 4; ++k) {
        floatx4 top = tl[k] + (tr[k] - tl[k]) * ax[k];
        floatx4 bot = bl[k] + (br[k] - bl[k]) * ax[k];
        floatx4 o   = top + (bot - top) * ay[k];
        __builtin_nontemporal_store(
            o, reinterpret_cast<floatx4*>(out + (size_t)(pix0 + k * W) * C + cg * 4));
    }
}

extern "C" void kernel_launch(void* const* d_in, const int* in_sizes, int n_in,
                              void* d_out, int out_size, void* d_ws, size_t ws_size,
                              hipStream_t stream) {
    const float* img  = (const float*)d_in[0];
    const float* flow = (const float*)d_in[1];
    float* out = (float*)d_out;

    constexpr int NBLK = 16384;
    InvWarpFlow_kernel<<<NBLK, 256, 0, stream>>>(img, flow, out);
}

// Round 6
// 112.186 us; speedup vs baseline: 1.3555x; 1.3555x over previous
//
#include <hip/hip_runtime.h>

// InvWarpFlow: out[b,y,x,c] = bilinear(img[b], (y + flow[b,y,x,0], x + flow[b,y,x,1]))
// (reference is dense_image_warp(img, -flow), so query = grid + flow)
// img:  [16,256,512,32] f32 ; flow: [16,256,512,2] f32 ; out: [16,256,512,32] f32
//
// R5 lesson: time scales with VMEM instruction count; prefetch = pure overhead.
// R4's MLP attempt silently failed: VGPR_Count=36 proves the compiler
// serialized the 16 gathers. This round: __launch_bounds__(256,1) frees the
// register budget and the code is phase-separated (addr -> all loads -> math)
// so all 16 img gathers are genuinely in flight per thread.

typedef float floatx4 __attribute__((ext_vector_type(4)));

__global__ __launch_bounds__(256, 1) void InvWarpFlow_kernel(
    const float* __restrict__ img,
    const float* __restrict__ flow,
    float* __restrict__ out)
{
    constexpr int H = 256, W = 512, C = 32;
    constexpr int TW = 8, TH = 16;                  // tile in pixels
    constexpr int TILES_X = W / TW;                 // 64
    constexpr int TILES_Y = H / TH;                 // 16
    constexpr int NBLK = 16 * TILES_X * TILES_Y;    // 16384
    constexpr int PER_XCD = NBLK / 8;               // 2048

    // XCD-chunked swizzle; within a chunk tx varies fastest (band sweep).
    int bid = blockIdx.x;
    int logical = (bid & 7) * PER_XCD + (bid >> 3);

    int tx = logical & (TILES_X - 1);
    int r  = logical >> 6;
    int ty = r & (TILES_Y - 1);
    int b  = r >> 4;

    int t  = threadIdx.x;
    int cg = t & 7;                  // channel group (float4)
    int s  = t >> 3;                 // pixel slot 0..31
    int lx = s & 7;
    int wv = s >> 3;                 // wave id 0..3

    int x  = tx * TW + lx;
    int y0 = ty * TH + wv * 4;       // this thread's 4 rows: y0..y0+3
    int pix0 = ((b << 8) + y0) * W + x;

    // Phase 1: flow loads (all independent).
    float2 f[4];
    #pragma unroll
    for (int k = 0; k < 4; ++k)
        f[k] = *reinterpret_cast<const float2*>(flow + (size_t)(pix0 + k * W) * 2);

    // Phase 2: compute all gather addresses (VALU only, closes flow loads).
    const float* ib = img + (size_t)b * H * W * C + cg * 4;
    const float* base[4];
    float ax[4], ay[4];
    #pragma unroll
    for (int k = 0; k < 4; ++k) {
        float qy = (float)(y0 + k) + f[k].x;
        float qx = (float)x + f[k].y;
        float fy = fminf(fmaxf(floorf(qy), 0.0f), (float)(H - 2));
        float fx = fminf(fmaxf(floorf(qx), 0.0f), (float)(W - 2));
        ay[k] = fminf(fmaxf(qy - fy, 0.0f), 1.0f);
        ax[k] = fminf(fmaxf(qx - fx, 0.0f), 1.0f);
        base[k] = ib + ((size_t)(int)fy * W + (int)fx) * C;
    }

    // Phase 3: issue ALL 16 img gathers before any use (needs ~64 VGPRs of
    // destinations -- launch_bounds(256,1) lifts the register cap).
    floatx4 tl[4], tr[4], bl[4], br[4];
    #pragma unroll
    for (int k = 0; k < 4; ++k) {
        tl[k] = *reinterpret_cast<const floatx4*>(base[k]);
        tr[k] = *reinterpret_cast<const floatx4*>(base[k] + C);
        bl[k] = *reinterpret_cast<const floatx4*>(base[k] + (size_t)W * C);
        br[k] = *reinterpret_cast<const floatx4*>(base[k] + (size_t)W * C + C);
    }

    // Phase 4: math + stores.
    #pragma unroll
    for (int k = 0; k < 4; ++k) {
        floatx4 top = tl[k] + (tr[k] - tl[k]) * ax[k];
        floatx4 bot = bl[k] + (br[k] - bl[k]) * ax[k];
        floatx4 o   = top + (bot - top) * ay[k];
        __builtin_nontemporal_store(
            o, reinterpret_cast<floatx4*>(out + (size_t)(pix0 + k * W) * C + cg * 4));
    }
}

extern "C" void kernel_launch(void* const* d_in, const int* in_sizes, int n_in,
                              void* d_out, int out_size, void* d_ws, size_t ws_size,
                              hipStream_t stream) {
    const float* img  = (const float*)d_in[0];
    const float* flow = (const float*)d_in[1];
    float* out = (float*)d_out;

    constexpr int NBLK = 16384;
    InvWarpFlow_kernel<<<NBLK, 256, 0, stream>>>(img, flow, out);
}

// Round 7
// 99.582 us; speedup vs baseline: 1.5270x; 1.1266x over previous
//
#include <hip/hip_runtime.h>

// InvWarpFlow: out[b,y,x,c] = bilinear(img[b], (y + flow[b,y,x,0], x + flow[b,y,x,1]))
// (reference is dense_image_warp(img, -flow), so query = grid + flow)
// img:  [16,256,512,32] f32 ; flow: [16,256,512,2] f32 ; out: [16,256,512,32] f32
//
// R6 lesson: the compiler's scheduler re-serializes the gathers no matter how
// the source is phased (VGPR stuck at 36). This round forces 16-deep MLP with
// inline-asm global_load_dwordx4 (volatile, ordered) + one s_waitcnt vmcnt(0)
// that ties all 16 destinations as "+v" operands so no use can be hoisted
// above the wait (r263/r282 hazard).

typedef float floatx4 __attribute__((ext_vector_type(4)));

__global__ __launch_bounds__(256, 1) void InvWarpFlow_kernel(
    const float* __restrict__ img,
    const float* __restrict__ flow,
    float* __restrict__ out)
{
    constexpr int H = 256, W = 512, C = 32;
    constexpr int TW = 8, TH = 16;                  // tile in pixels
    constexpr int TILES_X = W / TW;                 // 64
    constexpr int TILES_Y = H / TH;                 // 16
    constexpr int NBLK = 16 * TILES_X * TILES_Y;    // 16384
    constexpr int PER_XCD = NBLK / 8;               // 2048

    // XCD-chunked swizzle; within a chunk tx varies fastest (band sweep).
    int bid = blockIdx.x;
    int logical = (bid & 7) * PER_XCD + (bid >> 3);

    int tx = logical & (TILES_X - 1);
    int r  = logical >> 6;
    int ty = r & (TILES_Y - 1);
    int b  = r >> 4;

    int t  = threadIdx.x;
    int cg = t & 7;                  // channel group (float4)
    int s  = t >> 3;                 // pixel slot 0..31
    int lx = s & 7;
    int wv = s >> 3;                 // wave id 0..3

    int x  = tx * TW + lx;
    int y0 = ty * TH + wv * 4;       // this thread's 4 rows: y0..y0+3
    int pix0 = ((b << 8) + y0) * W + x;

    // Phase 1: flow loads (independent, close before address calc).
    float2 f[4];
    #pragma unroll
    for (int k = 0; k < 4; ++k)
        f[k] = *reinterpret_cast<const float2*>(flow + (size_t)(pix0 + k * W) * 2);

    // Phase 2: gather addresses.
    const float* ib = img + (size_t)b * H * W * C + cg * 4;
    const float* baseT[4];
    const float* baseB[4];
    float ax[4], ay[4];
    #pragma unroll
    for (int k = 0; k < 4; ++k) {
        float qy = (float)(y0 + k) + f[k].x;
        float qx = (float)x + f[k].y;
        float fy = fminf(fmaxf(floorf(qy), 0.0f), (float)(H - 2));
        float fx = fminf(fmaxf(floorf(qx), 0.0f), (float)(W - 2));
        ay[k] = fminf(fmaxf(qy - fy, 0.0f), 1.0f);
        ax[k] = fminf(fmaxf(qx - fx, 0.0f), 1.0f);
        baseT[k] = ib + ((size_t)(int)fy * W + (int)fx) * C;
        baseB[k] = baseT[k] + (size_t)W * C;
    }

    // Phase 3: ALL 16 img gathers issued via inline asm (cannot be re-sunk);
    // tr/br use the offset:128 immediate (C*4 bytes) off the same address.
    floatx4 tl[4], tr[4], bl[4], br[4];
    #pragma unroll
    for (int k = 0; k < 4; ++k) {
        asm volatile("global_load_dwordx4 %0, %2, off\n\t"
                     "global_load_dwordx4 %1, %2, off offset:128"
                     : "=&v"(tl[k]), "=&v"(tr[k]) : "v"(baseT[k]));
        asm volatile("global_load_dwordx4 %0, %2, off\n\t"
                     "global_load_dwordx4 %1, %2, off offset:128"
                     : "=&v"(bl[k]), "=&v"(br[k]) : "v"(baseB[k]));
    }

    // Single wait; every loaded vector is tied through it so no use can be
    // scheduled above the wait.
    asm volatile("s_waitcnt vmcnt(0)"
                 : "+v"(tl[0]), "+v"(tl[1]), "+v"(tl[2]), "+v"(tl[3]),
                   "+v"(tr[0]), "+v"(tr[1]), "+v"(tr[2]), "+v"(tr[3]),
                   "+v"(bl[0]), "+v"(bl[1]), "+v"(bl[2]), "+v"(bl[3]),
                   "+v"(br[0]), "+v"(br[1]), "+v"(br[2]), "+v"(br[3])
                 :: "memory");
    __builtin_amdgcn_sched_barrier(0);

    // Phase 4: math + stores.
    #pragma unroll
    for (int k = 0; k < 4; ++k) {
        floatx4 top = tl[k] + (tr[k] - tl[k]) * ax[k];
        floatx4 bot = bl[k] + (br[k] - bl[k]) * ax[k];
        floatx4 o   = top + (bot - top) * ay[k];
        __builtin_nontemporal_store(
            o, reinterpret_cast<floatx4*>(out + (size_t)(pix0 + k * W) * C + cg * 4));
    }
}

extern "C" void kernel_launch(void* const* d_in, const int* in_sizes, int n_in,
                              void* d_out, int out_size, void* d_ws, size_t ws_size,
                              hipStream_t stream) {
    const float* img  = (const float*)d_in[0];
    const float* flow = (const float*)d_in[1];
    float* out = (float*)d_out;

    constexpr int NBLK = 16384;
    InvWarpFlow_kernel<<<NBLK, 256, 0, stream>>>(img, flow, out);
}

// Round 9
// 99.223 us; speedup vs baseline: 1.5326x; 1.0036x over previous
//
#include <hip/hip_runtime.h>

// InvWarpFlow: out[b,y,x,c] = bilinear(img[b], (y + flow[b,y,x,0], x + flow[b,y,x,1]))
// img: [16,256,512,32] f32 ; flow: [16,256,512,2] f32 ; out: [16,256,512,32] f32
//
// R8's full-asm rolling pipeline faulted; retreat to R7's proven machinery
// (asm burst loads + tied-operand wait) with ONE safe extension: 2-deep quad
// pipeline. 32 gathers issued, vmcnt(16) -> compute/store quad A while quad
// B's 16 loads remain in flight, vmcnt(4) -> compute/store quad B. Waits are
// conservative-safe: the waited-for loads are always OLDER than any
// compiler-emitted store/spill, so miscounts only over-wait.

typedef float floatx4 __attribute__((ext_vector_type(4)));
typedef float floatx2 __attribute__((ext_vector_type(2)));

__global__ __launch_bounds__(256, 1) void InvWarpFlow_kernel(
    const float* __restrict__ img,
    const float* __restrict__ flow,
    float* __restrict__ out)
{
    constexpr int H = 256, W = 512, C = 32;
    constexpr int TW = 32;                     // x-slots per block
    constexpr int RPT = 8;                     // rows per thread (2 quads)
    constexpr int TILES_X = W / TW;            // 16
    constexpr int YSTR = H / RPT;              // 32
    constexpr int NBLK = 16 * TILES_X * YSTR;  // 8192
    constexpr int PER_XCD = NBLK / 8;          // 1024

    // XCD-chunked swizzle; tx fastest, then y-strip, then batch.
    int bid = blockIdx.x;
    int logical = (bid & 7) * PER_XCD + (bid >> 3);
    int tx = logical & (TILES_X - 1);
    int r  = logical >> 4;
    int ys = r & (YSTR - 1);
    int b  = r >> 5;

    int t  = threadIdx.x;
    int cg = t & 7;                  // channel group (16 B)
    int sl = t >> 3;                 // x-slot 0..31
    int x  = tx * TW + sl;
    int y0 = ys * RPT;

    const float* ibase = img  + (size_t)(b << 8) * W * C + cg * 4;
    const float* fbase = flow + ((size_t)((b << 8) + y0) * W + x) * 2;
    float*       obase = out  + ((size_t)((b << 8) + y0) * W + x) * C + cg * 4;

    // Phase 1: flow for all 8 rows (plain loads; compiler-managed waits).
    floatx2 f[RPT];
    #pragma unroll
    for (int k = 0; k < RPT; ++k)
        f[k] = *reinterpret_cast<const floatx2*>(fbase + (size_t)k * (W * 2));

    // Phase 2: all 8 gather addresses + weights.
    const float* bT[RPT];
    float ax[RPT], ay[RPT];
    #pragma unroll
    for (int k = 0; k < RPT; ++k) {
        float qy = (float)(y0 + k) + f[k].x;
        float qx = (float)x + f[k].y;
        float fy = fminf(fmaxf(floorf(qy), 0.0f), (float)(H - 2));
        float fx = fminf(fmaxf(floorf(qx), 0.0f), (float)(W - 2));
        ay[k] = fminf(fmaxf(qy - fy, 0.0f), 1.0f);
        ax[k] = fminf(fmaxf(qx - fx, 0.0f), 1.0f);
        bT[k] = ibase + ((size_t)(int)fy * W + (int)fx) * C;
    }

    // Phase 3: burst-issue ALL 32 img gathers (quad A = rows 0-3 first).
    floatx4 tl[RPT], tr[RPT], bl[RPT], br[RPT];
    #pragma unroll
    for (int k = 0; k < RPT; ++k) {
        const float* bB = bT[k] + (size_t)W * C;
        asm volatile("global_load_dwordx4 %0, %2, off\n\t"
                     "global_load_dwordx4 %1, %2, off offset:128"
                     : "=&v"(tl[k]), "=&v"(tr[k]) : "v"(bT[k]));
        asm volatile("global_load_dwordx4 %0, %2, off\n\t"
                     "global_load_dwordx4 %1, %2, off offset:128"
                     : "=&v"(bl[k]), "=&v"(br[k]) : "v"(bB));
    }

    // Wait A: leave the newest 16 (quad B) in flight.
    asm volatile("s_waitcnt vmcnt(16)"
        : "+v"(tl[0]), "+v"(tl[1]), "+v"(tl[2]), "+v"(tl[3]),
          "+v"(tr[0]), "+v"(tr[1]), "+v"(tr[2]), "+v"(tr[3]),
          "+v"(bl[0]), "+v"(bl[1]), "+v"(bl[2]), "+v"(bl[3]),
          "+v"(br[0]), "+v"(br[1]), "+v"(br[2]), "+v"(br[3]) :: "memory");
    __builtin_amdgcn_sched_barrier(0);

    // Compute + store quad A (B's loads still in flight underneath).
    #pragma unroll
    for (int k = 0; k < 4; ++k) {
        floatx4 top = tl[k] + (tr[k] - tl[k]) * ax[k];
        floatx4 bot = bl[k] + (br[k] - bl[k]) * ax[k];
        floatx4 o   = top + (bot - top) * ay[k];
        __builtin_nontemporal_store(
            o, reinterpret_cast<floatx4*>(obase + (size_t)k * (W * C)));
    }

    // Wait B: B's 16 loads are OLDER than A's 4 stores, so vmcnt(4)
    // guarantees B complete even if the compiler split/added stores.
    asm volatile("s_waitcnt vmcnt(4)"
        : "+v"(tl[4]), "+v"(tl[5]), "+v"(tl[6]), "+v"(tl[7]),
          "+v"(tr[4]), "+v"(tr[5]), "+v"(tr[6]), "+v"(tr[7]),
          "+v"(bl[4]), "+v"(bl[5]), "+v"(bl[6]), "+v"(bl[7]),
          "+v"(br[4]), "+v"(br[5]), "+v"(br[6]), "+v"(br[7]) :: "memory");
    __builtin_amdgcn_sched_barrier(0);

    // Compute + store quad B.
    #pragma unroll
    for (int k = 4; k < 8; ++k) {
        floatx4 top = tl[k] + (tr[k] - tl[k]) * ax[k];
        floatx4 bot = bl[k] + (br[k] - bl[k]) * ax[k];
        floatx4 o   = top + (bot - top) * ay[k];
        __builtin_nontemporal_store(
            o, reinterpret_cast<floatx4*>(obase + (size_t)k * (W * C)));
    }
}

extern "C" void kernel_launch(void* const* d_in, const int* in_sizes, int n_in,
                              void* d_out, int out_size, void* d_ws, size_t ws_size,
                              hipStream_t stream) {
    const float* img  = (const float*)d_in[0];
    const float* flow = (const float*)d_in[1];
    float* out = (float*)d_out;

    constexpr int NBLK = 8192;
    InvWarpFlow_kernel<<<NBLK, 256, 0, stream>>>(img, flow, out);
}